// Round 1
// baseline (427.961 us; speedup 1.0000x reference)
//
#include <hip/hip_runtime.h>
#include <cstdint>
#include <cstddef>

#define HH 128
#define WW 128
#define LL 16384   // HH*WW
#define BL 32768   // B*LL
#define STR 36     // LDS row stride for 32-ch window tiles (16B aligned rows)
#define OSTR 28    // LDS row stride for O tile [32][28]

// ---------------- k0: fold proj into fusion weight: Wc_t[in][o], bc[o] ----------------
__global__ __launch_bounds__(256) void k_combine(
    const float* __restrict__ proj_w, const float* __restrict__ proj_b,
    const float* __restrict__ fw, const float* __restrict__ fb,
    float* __restrict__ wc_t, float* __restrict__ bc)
{
  if (blockIdx.x == 200) {
    int o = threadIdx.x;
    if (o < 64) {
      float acc = proj_b[o];
      for (int m = 0; m < 64; ++m) acc = fmaf(proj_w[o*64+m], fb[m], acc);
      bc[o] = acc;
    }
    return;
  }
  int gid = blockIdx.x * 256 + threadIdx.x;   // < 51200
  int o  = gid & 63;
  int in = gid >> 6;                          // 0..799  (= c*25 + t)
  float acc = 0.f;
  for (int m = 0; m < 64; ++m) acc = fmaf(proj_w[o*64+m], fw[m*800+in], acc);
  wc_t[in*64 + o] = acc;
}

// ---------------- k1: LayerNorm + QKV, store q/k/v de-interleaved (c' = nh*16 + d) ----
__global__ __launch_bounds__(256) void k_ln_qkv(
    const float* __restrict__ x, const float* __restrict__ qkv_w,
    const float* __restrict__ qkv_b, const float* __restrict__ n1w,
    const float* __restrict__ n1b, float* __restrict__ qo,
    float* __restrict__ ko, float* __restrict__ vo)
{
  __shared__ float sW[96*32];
  __shared__ float sB[96];
  __shared__ float sNw[32], sNb[32];
  for (int i = threadIdx.x; i < 96*32; i += 256) sW[i] = qkv_w[i];
  if (threadIdx.x < 96) sB[threadIdx.x] = qkv_b[threadIdx.x];
  if (threadIdx.x < 32) { sNw[threadIdx.x] = n1w[threadIdx.x]; sNb[threadIdx.x] = n1b[threadIdx.x]; }
  __syncthreads();
  int gid = blockIdx.x * 256 + threadIdx.x;   // 0..BL-1
  int b = gid >> 14, l = gid & (LL - 1);
  const float* xp = x + (size_t)b * 32 * LL + l;   // x[b,c,l], stride LL per channel
  float xv[32];
  float mean = 0.f;
  #pragma unroll
  for (int c = 0; c < 32; ++c) { xv[c] = xp[(size_t)c * LL]; mean += xv[c]; }
  mean *= 0.03125f;
  float var = 0.f;
  #pragma unroll
  for (int c = 0; c < 32; ++c) { float d = xv[c] - mean; var = fmaf(d, d, var); }
  float rs = rsqrtf(var * 0.03125f + 1e-5f);
  #pragma unroll
  for (int c = 0; c < 32; ++c) xv[c] = (xv[c] - mean) * rs * sNw[c] + sNb[c];
  size_t base = (size_t)gid * 32;
  float* outs[3] = {qo, ko, vo};
  #pragma unroll
  for (int p = 0; p < 3; ++p) {
    float* op = outs[p] + base;
    for (int o = 0; o < 32; ++o) {
      const float* wr = &sW[(p*32 + o) * 32];
      float acc = sB[p*32 + o];
      #pragma unroll
      for (int c = 0; c < 32; ++c) acc = fmaf(xv[c], wr[c], acc);
      // original channel o -> head nh = o&1, dim d = o>>1 -> store at nh*16+d
      op[(o & 1) * 16 + (o >> 1)] = acc;
    }
  }
}

// ---------------- k2: per-location windowed attention + (fusion∘proj) ----------------
__global__ __launch_bounds__(64) void k_attn(
    const float* __restrict__ qi, const float* __restrict__ ki,
    const float* __restrict__ vi, const float* __restrict__ rel_table,
    const float* __restrict__ wct, const float* __restrict__ bc,
    float* __restrict__ y2)
{
  __shared__ __align__(16) float sQ[25*STR], sK[25*STR], sV[25*STR];
  __shared__ __align__(16) float sO[32*OSTR];
  __shared__ float sS[50*25];     // [nh*25+tq][tk]  (post-softmax probs)
  __shared__ float sRT[162];
  __shared__ float sPar[25];
  int lane = threadIdx.x;
  int bid  = blockIdx.x;          // b*LL + l
  int b = bid >> 14, l = bid & (LL - 1);
  int h = l >> 7,  w = l & (WW - 1);

  for (int i = lane; i < 162; i += 64) sRT[i] = rel_table[i];
  if (lane < 25) {
    int i = lane / 5, j = lane % 5;
    int h2 = h + i - 2, w2 = w + j - 2;
    bool valid = ((unsigned)h2 < HH) && ((unsigned)w2 < WW);
    sPar[lane] = (valid && (((h2 + w2) & 1) == 1)) ? 1.f : 0.f;
  }
  const float4 zero4 = make_float4(0.f, 0.f, 0.f, 0.f);
  // stage q/k/v windows: 25 positions x 32 ch, float4 granularity
  for (int idx = lane; idx < 200; idx += 64) {
    int t = idx >> 3, c4 = idx & 7;
    int i = t / 5, j = t % 5;
    int h2 = h + i - 2, w2 = w + j - 2;
    float4 qv = zero4, kv = zero4, vv = zero4;
    if (((unsigned)h2 < HH) && ((unsigned)w2 < WW)) {
      size_t off = ((size_t)(b * LL + h2 * WW + w2)) * 32 + c4 * 4;
      qv = *(const float4*)(qi + off);
      kv = *(const float4*)(ki + off);
      vv = *(const float4*)(vi + off);
    }
    *(float4*)(&sQ[t*STR + c4*4]) = qv;
    *(float4*)(&sK[t*STR + c4*4]) = kv;
    *(float4*)(&sV[t*STR + c4*4]) = vv;
  }
  __syncthreads();

  // scores + bias + mask + softmax: one (nh,tq) row per lane, 50 active
  if (lane < 50) {
    int nh = (lane >= 25) ? 1 : 0;
    int tq = lane - nh * 25;
    float qr[16];
    const float4* q4 = (const float4*)(&sQ[tq*STR + nh*16]);
    #pragma unroll
    for (int e = 0; e < 4; ++e) {
      float4 t4 = q4[e];
      qr[4*e] = t4.x; qr[4*e+1] = t4.y; qr[4*e+2] = t4.z; qr[4*e+3] = t4.w;
    }
    float s[25];
    int iq = tq / 5, jq = tq % 5;
    float parq = sPar[tq];
    float mx = -1e30f;
    #pragma unroll
    for (int tk = 0; tk < 25; ++tk) {
      const float4* k4 = (const float4*)(&sK[tk*STR + nh*16]);
      float acc = 0.f;
      #pragma unroll
      for (int e = 0; e < 4; ++e) {
        float4 t4 = k4[e];
        acc = fmaf(qr[4*e], t4.x, acc);
        acc = fmaf(qr[4*e+1], t4.y, acc);
        acc = fmaf(qr[4*e+2], t4.z, acc);
        acc = fmaf(qr[4*e+3], t4.w, acc);
      }
      int ik = tk / 5, jk = tk % 5;
      int rel = (iq - ik + 4) * 9 + (jq - jk + 4);
      float bias = sRT[rel*2 + nh];
      float msk = (parq * sPar[tk] == 1.f) ? 0.f : -100.f;
      float sc = fmaf(acc, 0.25f, bias) + msk;   // SCALE = HD^-0.5 = 0.25
      s[tk] = sc;
      mx = fmaxf(mx, sc);
    }
    float sum = 0.f;
    #pragma unroll
    for (int tk = 0; tk < 25; ++tk) { float e = __expf(s[tk] - mx); s[tk] = e; sum += e; }
    float inv = 1.f / sum;
    float* prow = &sS[lane * 25];
    #pragma unroll
    for (int tk = 0; tk < 25; ++tk) prow[tk] = s[tk] * inv;
  }
  __syncthreads();

  // PV: O[tq][c_out] = sum_tk P[nh][tq][tk] * V[tk][c_out]   (c_out = nh*16+d, matches layout)
  #pragma unroll
  for (int rep = 0; rep < 13; ++rep) {
    int idx = lane + rep * 64;
    if (idx < 800) {
      int tq = idx >> 5, c = idx & 31;
      int nh = c >> 4;
      const float* P = &sS[(nh*25 + tq) * 25];
      float acc = 0.f;
      #pragma unroll
      for (int tk = 0; tk < 25; ++tk) acc = fmaf(P[tk], sV[tk*STR + c], acc);
      sO[c*OSTR + tq] = acc;   // transposed store: [c][t]
    }
  }
  __syncthreads();

  // fused fusion+proj: y2[o] = bc[o] + sum_{in=c*25+t} O[in] * Wc_t[in][o]
  {
    int o = lane;
    float acc = bc[o];
    for (int c = 0; c < 32; ++c) {
      const float* orow = &sO[c*OSTR];
      const float* wr = wct + (size_t)(c*25)*64 + o;
      #pragma unroll
      for (int t = 0; t < 25; ++t)
        acc = fmaf(orow[t], wr[t*64], acc);   // coalesced 256B/instr across lanes
    }
    y2[(size_t)bid * 64 + o] = acc;
  }
}

// ---------------- k3: LN + MLP(GELU exact) + residual + transpose store --------------
__global__ __launch_bounds__(128, 1) void k_mlp(
    const float* __restrict__ y2, const float* __restrict__ n2w,
    const float* __restrict__ n2b, const float* __restrict__ w1,
    const float* __restrict__ b1, const float* __restrict__ w2,
    const float* __restrict__ b2, float* __restrict__ out)
{
  __shared__ __align__(16) float sW1[128*64];
  __shared__ __align__(16) float sW2[64*128];
  __shared__ float sNw[64], sNb[64], sB1[128], sB2[64];
  int tid = threadIdx.x;
  for (int i = tid; i < 128*64; i += 128) sW1[i] = w1[i];
  for (int i = tid; i < 64*128; i += 128) sW2[i] = w2[i];
  if (tid < 64) { sNw[tid] = n2w[tid]; sNb[tid] = n2b[tid]; sB2[tid] = b2[tid]; }
  sB1[tid] = b1[tid];
  __syncthreads();
  int gid = blockIdx.x * 128 + tid;
  int b = gid >> 14, l = gid & (LL - 1);
  float yv[64], hn[64], macc[64];
  const float* yp = y2 + (size_t)gid * 64;
  float mean = 0.f;
  #pragma unroll
  for (int c = 0; c < 64; ++c) { yv[c] = yp[c]; mean += yv[c]; }
  mean *= (1.f/64.f);
  float var = 0.f;
  #pragma unroll
  for (int c = 0; c < 64; ++c) { float d = yv[c] - mean; var = fmaf(d, d, var); }
  float rs = rsqrtf(var * (1.f/64.f) + 1e-5f);
  #pragma unroll
  for (int c = 0; c < 64; ++c) hn[c] = (yv[c] - mean) * rs * sNw[c] + sNb[c];
  #pragma unroll
  for (int o = 0; o < 64; ++o) macc[o] = sB2[o];
  for (int j4 = 0; j4 < 32; ++j4) {
    float g[4];
    #pragma unroll
    for (int u = 0; u < 4; ++u) {
      int j = j4*4 + u;
      const float* wr = &sW1[j*64];
      float hj = sB1[j];
      #pragma unroll
      for (int c = 0; c < 64; ++c) hj = fmaf(hn[c], wr[c], hj);
      g[u] = 0.5f * hj * (1.f + erff(hj * 0.70710678118f));   // exact GELU
    }
    #pragma unroll
    for (int o = 0; o < 64; ++o) {
      const float4 w4 = *(const float4*)(&sW2[o*128 + j4*4]);
      macc[o] = fmaf(g[0], w4.x, fmaf(g[1], w4.y, fmaf(g[2], w4.z, fmaf(g[3], w4.w, macc[o]))));
    }
  }
  size_t ob = (size_t)b * 64 * LL + l;
  #pragma unroll
  for (int o = 0; o < 64; ++o) out[ob + (size_t)o * LL] = yv[o] + macc[o];
}

extern "C" void kernel_launch(void* const* d_in, const int* in_sizes, int n_in,
                              void* d_out, int out_size, void* d_ws, size_t ws_size,
                              hipStream_t stream) {
  const float* x         = (const float*)d_in[0];
  const float* qkv_w     = (const float*)d_in[1];
  const float* qkv_b     = (const float*)d_in[2];
  const float* rel_table = (const float*)d_in[3];
  const float* n1w       = (const float*)d_in[4];
  const float* n1b       = (const float*)d_in[5];
  const float* n2w       = (const float*)d_in[6];
  const float* n2b       = (const float*)d_in[7];
  const float* proj_w    = (const float*)d_in[8];
  const float* proj_b    = (const float*)d_in[9];
  const float* fw        = (const float*)d_in[10];
  const float* fb        = (const float*)d_in[11];
  const float* w1        = (const float*)d_in[12];
  const float* b1        = (const float*)d_in[13];
  const float* w2        = (const float*)d_in[14];
  const float* b2        = (const float*)d_in[15];

  float* ws  = (float*)d_ws;
  float* q   = ws;                     // BL*32 = 1,048,576 floats
  float* k   = ws + 1048576;
  float* v   = ws + 2097152;
  float* y2  = ws + 3145728;           // BL*64 = 2,097,152 floats
  float* wct = ws + 5242880;           // 800*64 = 51,200 floats
  float* bc  = ws + 5294080;           // 64 floats
  float* out = (float*)d_out;

  k_combine<<<201, 256, 0, stream>>>(proj_w, proj_b, fw, fb, wct, bc);
  k_ln_qkv<<<128, 256, 0, stream>>>(x, qkv_w, qkv_b, n1w, n1b, q, k, v);
  k_attn<<<32768, 64, 0, stream>>>(q, k, v, rel_table, wct, bc, y2);
  k_mlp<<<256, 128, 0, stream>>>(y2, n2w, n2b, w1, b1, w2, b2, out);
}